// Round 7
// baseline (160.560 us; speedup 1.0000x reference)
//
#include <hip/hip_runtime.h>
#include <cmath>

// CNEncoder reduced form (MCMC/graph path cancels; see round-0 derivation):
//   P_i = sum_j nx[i,j]; S_i = sum_j rf[i,j]; scale_i = P_i/(S_i+EPS)
//   t = rf*scale; global tmin/tmax/mean -> affine out = rf*(scale_i*A)+B
//   reg_loss = sum(rf^2)*1e-4
// st = sum_i sc_i*S_i computed as sum_i P_i (rel. err ~7e-12).
//
// L3 choreography (verified r5/r6: k_stats FETCH ~= nx only):
//   nx NT loads (evict-first), rf normal loads (L3-resident),
//   out NT stores (doesn't evict rf).
//
// r6 post-mortem: stats pass latency-bound at 45% occupancy with bursty
// load issue. This round: 2 rows/wave (10000 waves -> full occupancy) +
// manual 2-stage register pipeline (prefetch next iter's 4 loads before
// consuming current) -> continuous load issue per wave.

static constexpr int NS = 20000;
static constexpr int NG = 3000;
static constexpr int G4 = NG / 4;        // 750 fv4/row, row stride 12000 B
static constexpr int RW = 2;             // rows per wave
static constexpr int NWAVE = NS / RW;    // 10000 waves
static constexpr int NB = NWAVE / 4;     // 2500 blocks of 4 waves
static constexpr float EPS = 1e-8f;

typedef float fv4 __attribute__((ext_vector_type(4)));

// ws floats: [0,NS) S | [NS,2NS) P | [2NS,2NS+NWAVE) PST | +NWAVE PSQ
//            | +2*NWAVE PMN | +3*NWAVE PMX | then AB[2]

// ---- pass 1: per-row stats, 2 rows/wave, pipelined loads ----
__global__ __launch_bounds__(256) void k_stats(
    const fv4* __restrict__ nx, const fv4* __restrict__ rf,
    float* __restrict__ S, float* __restrict__ P,
    float* __restrict__ PST, float* __restrict__ PSQ,
    float* __restrict__ PMN, float* __restrict__ PMX)
{
    const int wid  = threadIdx.x >> 6;
    const int lane = threadIdx.x & 63;
    const int w    = blockIdx.x * 4 + wid;   // 0..NWAVE-1
    const int row0 = w * RW;
    const fv4* r0 = rf + (size_t)row0 * G4;
    const fv4* r1 = r0 + G4;
    const fv4* n0 = nx + (size_t)row0 * G4;
    const fv4* n1 = n0 + G4;

    float s0 = 0.f, s1 = 0.f, p0 = 0.f, p1 = 0.f, q = 0.f;
    float mn0 = INFINITY, mn1 = INFINITY, mx0 = -INFINITY, mx1 = -INFINITY;

    // 750 = 11*64 + 46: 11 uniform iterations + 46-lane tail.
    // 2-stage pipeline: prefetch i+1 while accumulating i.
    fv4 a0 = r0[lane];
    fv4 a1 = r1[lane];
    fv4 b0 = __builtin_nontemporal_load(n0 + lane);
    fv4 b1 = __builtin_nontemporal_load(n1 + lane);

    #pragma unroll
    for (int i = 0; i < 11; ++i) {
        int cn = lane + (i + 1) * 64;
        if (cn > G4 - 1) cn = G4 - 1;          // clamp: broadcast, masked later
        fv4 ta0 = r0[cn];
        fv4 ta1 = r1[cn];
        fv4 tb0 = __builtin_nontemporal_load(n0 + cn);
        fv4 tb1 = __builtin_nontemporal_load(n1 + cn);

        s0 += (a0.x + a0.y) + (a0.z + a0.w);
        s1 += (a1.x + a1.y) + (a1.z + a1.w);
        q  += a0.x * a0.x + a0.y * a0.y + a0.z * a0.z + a0.w * a0.w;
        q  += a1.x * a1.x + a1.y * a1.y + a1.z * a1.z + a1.w * a1.w;
        mn0 = fminf(mn0, fminf(fminf(a0.x, a0.y), fminf(a0.z, a0.w)));
        mn1 = fminf(mn1, fminf(fminf(a1.x, a1.y), fminf(a1.z, a1.w)));
        mx0 = fmaxf(mx0, fmaxf(fmaxf(a0.x, a0.y), fmaxf(a0.z, a0.w)));
        mx1 = fmaxf(mx1, fmaxf(fmaxf(a1.x, a1.y), fmaxf(a1.z, a1.w)));
        p0 += (b0.x + b0.y) + (b0.z + b0.w);
        p1 += (b1.x + b1.y) + (b1.z + b1.w);

        a0 = ta0; a1 = ta1; b0 = tb0; b1 = tb1;
    }
    if (lane < G4 - 11 * 64) {                  // tail: lanes 0..45
        s0 += (a0.x + a0.y) + (a0.z + a0.w);
        s1 += (a1.x + a1.y) + (a1.z + a1.w);
        q  += a0.x * a0.x + a0.y * a0.y + a0.z * a0.z + a0.w * a0.w;
        q  += a1.x * a1.x + a1.y * a1.y + a1.z * a1.z + a1.w * a1.w;
        mn0 = fminf(mn0, fminf(fminf(a0.x, a0.y), fminf(a0.z, a0.w)));
        mn1 = fminf(mn1, fminf(fminf(a1.x, a1.y), fminf(a1.z, a1.w)));
        mx0 = fmaxf(mx0, fmaxf(fmaxf(a0.x, a0.y), fmaxf(a0.z, a0.w)));
        mx1 = fmaxf(mx1, fmaxf(fmaxf(a1.x, a1.y), fmaxf(a1.z, a1.w)));
        p0 += (b0.x + b0.y) + (b0.z + b0.w);
        p1 += (b1.x + b1.y) + (b1.z + b1.w);
    }

    // 9 independent 6-step shuffle chains
    #pragma unroll
    for (int off = 32; off > 0; off >>= 1) {
        s0 += __shfl_down(s0, off);
        s1 += __shfl_down(s1, off);
        p0 += __shfl_down(p0, off);
        p1 += __shfl_down(p1, off);
        q  += __shfl_down(q,  off);
        mn0 = fminf(mn0, __shfl_down(mn0, off));
        mn1 = fminf(mn1, __shfl_down(mn1, off));
        mx0 = fmaxf(mx0, __shfl_down(mx0, off));
        mx1 = fmaxf(mx1, __shfl_down(mx1, off));
    }

    if (lane == 0) {
        S[row0] = s0; S[row0 + 1] = s1;
        P[row0] = p0; P[row0 + 1] = p1;
        const float sc0 = p0 / (s0 + EPS);
        const float sc1 = p1 / (s1 + EPS);
        PST[w] = p0 + p1;
        PSQ[w] = q;
        PMN[w] = fminf(mn0 * sc0, mn1 * sc1);
        PMX[w] = fmaxf(mx0 * sc0, mx1 * sc1);
    }
}

// ---- pass 2: fold NWAVE wave partials into {A,B} and reg_loss ----
__global__ __launch_bounds__(256) void k_scalars(
    const float* __restrict__ PST, const float* __restrict__ PSQ,
    const float* __restrict__ PMN, const float* __restrict__ PMX,
    float* __restrict__ AB, float* __restrict__ loss_out)
{
    double st = 0.0, sq = 0.0;
    float tmn = INFINITY, tmx = -INFINITY;
    for (int i = threadIdx.x; i < NWAVE; i += 256) {
        st += (double)PST[i];
        sq += (double)PSQ[i];
        tmn = fminf(tmn, PMN[i]);
        tmx = fmaxf(tmx, PMX[i]);
    }
    #pragma unroll
    for (int off = 32; off > 0; off >>= 1) {
        st += __shfl_down(st, off);
        sq += __shfl_down(sq, off);
        tmn = fminf(tmn, __shfl_down(tmn, off));
        tmx = fmaxf(tmx, __shfl_down(tmx, off));
    }
    __shared__ double lst[4], lsq[4];
    __shared__ float lmn[4], lmx[4];
    const int wid = threadIdx.x >> 6;
    if ((threadIdx.x & 63) == 0) { lst[wid] = st; lsq[wid] = sq; lmn[wid] = tmn; lmx[wid] = tmx; }
    __syncthreads();
    if (threadIdx.x == 0) {
        st  = (lst[0] + lst[1]) + (lst[2] + lst[3]);
        sq  = (lsq[0] + lsq[1]) + (lsq[2] + lsq[3]);
        tmn = fminf(fminf(lmn[0], lmn[1]), fminf(lmn[2], lmn[3]));
        tmx = fmaxf(fmaxf(lmx[0], lmx[1]), fmaxf(lmx[2], lmx[3]));
        const float rmin = tmn * 0.8f;
        const float rmax = tmx * 1.2f;
        const float a = (rmax - rmin) / (tmx - tmn + EPS);
        const float mean_t = (float)(st / (double)((long long)NS * (long long)NG));
        const float mean_u = (mean_t - tmn) * a + rmin;
        AB[0] = a / mean_u;
        AB[1] = (rmin - tmn * a) / mean_u;
        *loss_out = (float)(sq * 1e-4);
    }
}

// ---- pass 3: out = rf*c_row + B; wave per row; NT stores ----
__global__ __launch_bounds__(256) void k_finalize(
    const fv4* __restrict__ rf,
    const float* __restrict__ S, const float* __restrict__ P,
    const float* __restrict__ AB,
    fv4* __restrict__ out)
{
    const int row  = blockIdx.x * 4 + (threadIdx.x >> 6);
    const int lane = threadIdx.x & 63;
    const float A = AB[0], B = AB[1];
    const float c = (P[row] / (S[row] + EPS)) * A;
    const fv4* r = rf + (size_t)row * G4;
    fv4* o = out + (size_t)row * G4;
    for (int i = lane; i < G4; i += 64) {
        fv4 a = r[i];
        fv4 v;
        v.x = fmaf(a.x, c, B);
        v.y = fmaf(a.y, c, B);
        v.z = fmaf(a.z, c, B);
        v.w = fmaf(a.w, c, B);
        __builtin_nontemporal_store(v, o + i);
    }
}

extern "C" void kernel_launch(void* const* d_in, const int* in_sizes, int n_in,
                              void* d_out, int out_size, void* d_ws, size_t ws_size,
                              hipStream_t stream) {
    const float* nx = (const float*)d_in[0];   // norm_x
    const float* rf = (const float*)d_in[1];   // reconstructed_features
    // d_in[2] (edge_index) unused: effect on output < 1e-11 relative.
    float* out = (float*)d_out;
    float* ws  = (float*)d_ws;
    float* S   = ws;
    float* P   = ws + NS;
    float* PST = ws + 2 * NS;
    float* PSQ = PST + NWAVE;
    float* PMN = PST + 2 * NWAVE;
    float* PMX = PST + 3 * NWAVE;
    float* AB  = PST + 4 * NWAVE;
    float* loss_out = out + (out_size - 1);

    k_stats   <<<NB,     256, 0, stream>>>((const fv4*)nx, (const fv4*)rf,
                                           S, P, PST, PSQ, PMN, PMX);
    k_scalars <<<1,      256, 0, stream>>>(PST, PSQ, PMN, PMX, AB, loss_out);
    k_finalize<<<NS / 4, 256, 0, stream>>>((const fv4*)rf, S, P, AB, (fv4*)out);
}